// Round 1
// baseline (1734.352 us; speedup 1.0000x reference)
//
#include <hip/hip_runtime.h>
#include <hip/hip_bf16.h>

#define B_DIM 8
#define S_DIM 1024
#define D_DIM 1024
#define N_DIM 256
#define M_ROWS (B_DIM * S_DIM) /* 8192 */

typedef __attribute__((ext_vector_type(8))) short bf16x8;
typedef __attribute__((ext_vector_type(8))) unsigned short u16x8;
typedef __attribute__((ext_vector_type(4))) float f32x4;

static __device__ __forceinline__ unsigned short f2bf(float f) {
  union { __hip_bfloat16 h; unsigned short s; } u;
  u.h = __float2bfloat16(f);
  return u.s;
}

// ---------------------------------------------------------------------------
// GEMM1: KV[8192][512] = x[8192][1024] @ [Wk;Wv]([512][1024])^T   (bf16 MFMA)
// ---------------------------------------------------------------------------
__global__ __launch_bounds__(256) void gemm_kv(const float* __restrict__ x,
                                               const float* __restrict__ Wk,
                                               const float* __restrict__ Wv,
                                               float* __restrict__ KV) {
  __shared__ unsigned short lsA[128 * 40];
  __shared__ unsigned short lsB[128 * 40];
  const int tid = threadIdx.x;
  const int row0 = blockIdx.y * 128;
  const int col0 = blockIdx.x * 128;
  const float* Bsrc = (col0 < 256) ? (Wk + (size_t)col0 * 1024)
                                   : (Wv + (size_t)(col0 - 256) * 1024);
  const int sr = tid >> 1, sh = tid & 1;
  const float* ap = x + (size_t)(row0 + sr) * 1024 + sh * 16;
  const float* bp = Bsrc + (size_t)sr * 1024 + sh * 16;
  unsigned short* wa = &lsA[sr * 40 + sh * 16];
  unsigned short* wb = &lsB[sr * 40 + sh * 16];

  const int lane = tid & 63;
  const int w = tid >> 6, wr = w >> 1, wc = w & 1;
  const int fr = lane & 15, fk = lane >> 4;

  f32x4 acc[4][4];
#pragma unroll
  for (int m = 0; m < 4; ++m)
#pragma unroll
    for (int n = 0; n < 4; ++n) acc[m][n] = (f32x4){0.f, 0.f, 0.f, 0.f};

  for (int kt = 0; kt < 32; ++kt) {
    const float* a = ap + kt * 32;
    const float* b = bp + kt * 32;
    f32x4 A0 = *(const f32x4*)(a + 0), A1 = *(const f32x4*)(a + 4);
    f32x4 A2 = *(const f32x4*)(a + 8), A3 = *(const f32x4*)(a + 12);
    f32x4 B0 = *(const f32x4*)(b + 0), B1 = *(const f32x4*)(b + 4);
    f32x4 B2 = *(const f32x4*)(b + 8), B3 = *(const f32x4*)(b + 12);
    u16x8 pa0, pa1, pb0, pb1;
#pragma unroll
    for (int e = 0; e < 4; ++e) {
      pa0[e] = f2bf(A0[e]); pa0[e + 4] = f2bf(A1[e]);
      pa1[e] = f2bf(A2[e]); pa1[e + 4] = f2bf(A3[e]);
      pb0[e] = f2bf(B0[e]); pb0[e + 4] = f2bf(B1[e]);
      pb1[e] = f2bf(B2[e]); pb1[e + 4] = f2bf(B3[e]);
    }
    *(u16x8*)wa = pa0; *(u16x8*)(wa + 8) = pa1;
    *(u16x8*)wb = pb0; *(u16x8*)(wb + 8) = pb1;
    __syncthreads();
    bf16x8 af[4], bfr[4];
#pragma unroll
    for (int m = 0; m < 4; ++m)
      af[m] = *(const bf16x8*)(&lsA[(wr * 64 + m * 16 + fr) * 40 + fk * 8]);
#pragma unroll
    for (int n = 0; n < 4; ++n)
      bfr[n] = *(const bf16x8*)(&lsB[(wc * 64 + n * 16 + fr) * 40 + fk * 8]);
#pragma unroll
    for (int m = 0; m < 4; ++m)
#pragma unroll
      for (int n = 0; n < 4; ++n)
        acc[m][n] = __builtin_amdgcn_mfma_f32_16x16x32_bf16(af[m], bfr[n],
                                                            acc[m][n], 0, 0, 0);
    __syncthreads();
  }
#pragma unroll
  for (int m = 0; m < 4; ++m)
#pragma unroll
    for (int n = 0; n < 4; ++n) {
      const int col = col0 + wc * 64 + n * 16 + fr;
#pragma unroll
      for (int r = 0; r < 4; ++r) {
        const int row = row0 + wr * 64 + m * 16 + fk * 4 + r;
        KV[(size_t)row * 512 + col] = acc[m][n][r];
      }
    }
}

// ---------------------------------------------------------------------------
// gate[8192] = sigmoid(x @ Wg^T + bg)
// ---------------------------------------------------------------------------
__global__ __launch_bounds__(256) void gate_kernel(const float* __restrict__ x,
                                                   const float* __restrict__ Wg,
                                                   const float* __restrict__ bg,
                                                   float* __restrict__ gate) {
  const int row = blockIdx.x * 4 + (threadIdx.x >> 6);
  const int lane = threadIdx.x & 63;
  const f32x4* xr = (const f32x4*)(x + (size_t)row * 1024);
  const f32x4* wg = (const f32x4*)Wg;
  float s = 0.f;
#pragma unroll
  for (int c = 0; c < 4; ++c) {
    f32x4 a = xr[lane + 64 * c];
    f32x4 wv = wg[lane + 64 * c];
    s += a[0] * wv[0] + a[1] * wv[1] + a[2] * wv[2] + a[3] * wv[3];
  }
#pragma unroll
  for (int off = 32; off >= 1; off >>= 1) s += __shfl_xor(s, off, 64);
  if (lane == 0) gate[row] = 1.f / (1.f + __expf(-(s + bg[0])));
}

// ---------------------------------------------------------------------------
// Sequential scan: 1 block per batch, 256 threads, thread (i,k).
// State in registers: w1[i][:,k], w2[i][:,k], w2T[i][:,k].
// ---------------------------------------------------------------------------
__global__ __launch_bounds__(256) void scan_kernel(const float* __restrict__ KV,
                                                   const float* __restrict__ gate,
                                                   unsigned short* __restrict__ ysbf,
                                                   float* __restrict__ err_out) {
  const int b = blockIdx.x;
  const int tid = threadIdx.x;
  const int i = tid >> 4, k = tid & 15;
  const int lane = tid & 63;
  const int gbase = lane & 48;
  const int wid = tid >> 6;

  __shared__ float hidT[2][256];
  __shared__ __align__(16) float red[2][4];

  float w1c[16], w2c[16], w2t[16];
#pragma unroll
  for (int j = 0; j < 16; ++j) {
    float v = (j == k) ? 1.f : 0.f;
    w1c[j] = v; w2c[j] = v; w2t[j] = v;
  }
  float strength = 0.f, last_seen = 0.f, pend = 0.f;

  const float* Kb = KV + (size_t)b * S_DIM * 512;
  const float* Gb = gate + (size_t)b * S_DIM;
  unsigned short* Yb = ysbf + (size_t)b * S_DIM * 256;
  float* Eb = err_out + (size_t)b * S_DIM;

  // 2-deep prefetch
  float kt_c = Kb[tid], vt_c = Kb[256 + tid], g_c = Gb[0];
  float kt_n = Kb[512 + tid], vt_n = Kb[512 + 256 + tid], g_n = Gb[1];
  float kt_n2 = 0.f, vt_n2 = 0.f, g_n2 = 0.f;

  float ktj[16];
#pragma unroll
  for (int j = 0; j < 16; ++j) ktj[j] = __shfl(kt_c, gbase + j, 64);

  for (int s = 0; s < S_DIM; ++s) {
    const int pb = s & 1;
    const float t = (float)(s + 1);

    // hidden[i][k] = sum_j kt[i][j] * w1[i][j][k]
    float a0 = 0.f, a1 = 0.f, a2 = 0.f, a3 = 0.f;
#pragma unroll
    for (int j = 0; j < 16; j += 4) {
      a0 = fmaf(ktj[j], w1c[j], a0);
      a1 = fmaf(ktj[j + 1], w1c[j + 1], a1);
      a2 = fmaf(ktj[j + 2], w1c[j + 2], a2);
      a3 = fmaf(ktj[j + 3], w1c[j + 3], a3);
    }
    const float hidden = (a0 + a1) + (a2 + a3);
    hidT[pb][k * 16 + i] = hidden;

    // prefetch s+2
    if (s + 2 < S_DIM) {
      const float* p = Kb + (size_t)(s + 2) * 512;
      kt_n2 = p[tid]; vt_n2 = p[256 + tid]; g_n2 = Gb[s + 2];
    }
    __syncthreads();

    // transpose reads
    float hj[16];
    {
      const f32x4* hp = (const f32x4*)&hidT[pb][i * 16];
      f32x4 q0 = hp[0], q1 = hp[1], q2 = hp[2], q3 = hp[3];
#pragma unroll
      for (int e = 0; e < 4; ++e) {
        hj[e] = q0[e]; hj[4 + e] = q1[e]; hj[8 + e] = q2[e]; hj[12 + e] = q3[e];
      }
    }
    const float hkk = hidT[pb][tid];

    // deferred strength update using step s-1's err_norm
    if (s > 0) {
      f32x4 r4 = *(const f32x4*)&red[1 - pb][0];
      float en = sqrtf(r4[0] + r4[1] + r4[2] + r4[3]);
      strength += pend / (1.f + en);
      if (tid == 0) Eb[s - 1] = en;
    }
    const float delta = t - last_seen;
    const float tg = 1.f / fmaxf(log1pf(delta * 0.1f), 1.f);
    const float df = 0.05f / (1.f + strength * tg);
    const float am = 1.f - df;

    // vt_pred[i][k] = sum_j hidden[j][i] * w2[i][j][k]
    float v0 = 0.f, v1 = 0.f, v2 = 0.f, v3 = 0.f;
#pragma unroll
    for (int j = 0; j < 16; j += 4) {
      v0 = fmaf(hj[j], w2c[j], v0);
      v1 = fmaf(hj[j + 1], w2c[j + 1], v1);
      v2 = fmaf(hj[j + 2], w2c[j + 2], v2);
      v3 = fmaf(hj[j + 3], w2c[j + 3], v3);
    }
    const float vt_pred = (v0 + v1) + (v2 + v3);
    Yb[(size_t)s * 256 + k * 16 + i] = f2bf(vt_pred);

    const float err = vt_pred - vt_c;

    float errj[16];
#pragma unroll
    for (int j = 0; j < 16; ++j) errj[j] = __shfl(err, gbase + j, 64);

    // cross-workgroup err^2 reduce (consumed next step)
    float e2 = err * err;
#pragma unroll
    for (int off = 32; off >= 1; off >>= 1) e2 += __shfl_xor(e2, off, 64);
    if (lane == 0) red[pb][wid] = e2;

    // grad_h[i][k] = sum_j err[i][j] * w2[i][k][j]
    float g0 = 0.f, g1 = 0.f, g2 = 0.f, g3 = 0.f;
#pragma unroll
    for (int j = 0; j < 16; j += 4) {
      g0 = fmaf(errj[j], w2t[j], g0);
      g1 = fmaf(errj[j + 1], w2t[j + 1], g1);
      g2 = fmaf(errj[j + 2], w2t[j + 2], g2);
      g3 = fmaf(errj[j + 3], w2t[j + 3], g3);
    }
    const float gh = (g0 + g1) + (g2 + g3);

    const float slr = 0.1f * g_c;
    const float sg = slr * gh;
    const float se = slr * err;
    const float sh2 = slr * hkk;
#pragma unroll
    for (int j = 0; j < 16; ++j) {
      const float idv = (j == k) ? df : 0.f;
      w1c[j] = fmaf(w1c[j] - sg * ktj[j], am, idv);
      w2c[j] = fmaf(w2c[j] - se * hj[j], am, idv);
      w2t[j] = fmaf(w2t[j] - sh2 * errj[j], am, idv);
    }

    // activity / spacing / last_seen
    float s2 = 0.f;
#pragma unroll
    for (int j = 0; j < 16; ++j) s2 = fmaf(ktj[j], ktj[j], s2);
    const float act = sqrtf(s2);
    pend = log1pf(delta) * act * g_c * 0.05f;
    if (act > 0.1f) last_seen = t;

    // rotate prefetch, shuffle next ktj
    kt_c = kt_n; vt_c = vt_n; g_c = g_n;
    kt_n = kt_n2; vt_n = vt_n2; g_n = g_n2;
#pragma unroll
    for (int j = 0; j < 16; ++j) ktj[j] = __shfl(kt_c, gbase + j, 64);
  }
  __syncthreads();
  if (tid == 0) {
    const f32x4 r4 = *(const f32x4*)&red[1][0]; // s=1023 parity = 1
    Eb[S_DIM - 1] = sqrtf(r4[0] + r4[1] + r4[2] + r4[3]);
  }
}

// ---------------------------------------------------------------------------
// GEMM2: out[8192][1024] = ys[8192][256](bf16) @ Wo([1024][256])^T + bo
// ---------------------------------------------------------------------------
__global__ __launch_bounds__(256) void gemm_out(const unsigned short* __restrict__ ysbf,
                                                const float* __restrict__ Wo,
                                                const float* __restrict__ bo,
                                                float* __restrict__ out) {
  __shared__ unsigned short lsA[128 * 40];
  __shared__ unsigned short lsB[128 * 40];
  const int tid = threadIdx.x;
  const int row0 = blockIdx.y * 128;
  const int col0 = blockIdx.x * 128;
  const int sr = tid >> 1, sh = tid & 1;
  const unsigned short* ap = ysbf + (size_t)(row0 + sr) * 256 + sh * 16;
  const float* bp = Wo + (size_t)(col0 + sr) * 256 + sh * 16;
  unsigned short* wa = &lsA[sr * 40 + sh * 16];
  unsigned short* wb = &lsB[sr * 40 + sh * 16];

  const int lane = tid & 63;
  const int w = tid >> 6, wr = w >> 1, wc = w & 1;
  const int fr = lane & 15, fk = lane >> 4;

  f32x4 acc[4][4];
#pragma unroll
  for (int m = 0; m < 4; ++m)
#pragma unroll
    for (int n = 0; n < 4; ++n) acc[m][n] = (f32x4){0.f, 0.f, 0.f, 0.f};

  for (int kt = 0; kt < 8; ++kt) {
    u16x8 pa0 = *(const u16x8*)(ap + kt * 32);
    u16x8 pa1 = *(const u16x8*)(ap + kt * 32 + 8);
    const float* bq = bp + kt * 32;
    f32x4 B0 = *(const f32x4*)(bq + 0), B1 = *(const f32x4*)(bq + 4);
    f32x4 B2 = *(const f32x4*)(bq + 8), B3 = *(const f32x4*)(bq + 12);
    u16x8 pb0, pb1;
#pragma unroll
    for (int e = 0; e < 4; ++e) {
      pb0[e] = f2bf(B0[e]); pb0[e + 4] = f2bf(B1[e]);
      pb1[e] = f2bf(B2[e]); pb1[e + 4] = f2bf(B3[e]);
    }
    *(u16x8*)wa = pa0; *(u16x8*)(wa + 8) = pa1;
    *(u16x8*)wb = pb0; *(u16x8*)(wb + 8) = pb1;
    __syncthreads();
    bf16x8 af[4], bfr[4];
#pragma unroll
    for (int m = 0; m < 4; ++m)
      af[m] = *(const bf16x8*)(&lsA[(wr * 64 + m * 16 + fr) * 40 + fk * 8]);
#pragma unroll
    for (int n = 0; n < 4; ++n)
      bfr[n] = *(const bf16x8*)(&lsB[(wc * 64 + n * 16 + fr) * 40 + fk * 8]);
#pragma unroll
    for (int m = 0; m < 4; ++m)
#pragma unroll
      for (int n = 0; n < 4; ++n)
        acc[m][n] = __builtin_amdgcn_mfma_f32_16x16x32_bf16(af[m], bfr[n],
                                                            acc[m][n], 0, 0, 0);
    __syncthreads();
  }
#pragma unroll
  for (int m = 0; m < 4; ++m)
#pragma unroll
    for (int n = 0; n < 4; ++n) {
      const int col = col0 + wc * 64 + n * 16 + fr;
      const float bias = bo[col];
#pragma unroll
      for (int r = 0; r < 4; ++r) {
        const int row = row0 + wr * 64 + m * 16 + fk * 4 + r;
        out[(size_t)row * 1024 + col] = acc[m][n][r] + bias;
      }
    }
}

// ---------------------------------------------------------------------------
extern "C" void kernel_launch(void* const* d_in, const int* in_sizes, int n_in,
                              void* d_out, int out_size, void* d_ws, size_t ws_size,
                              hipStream_t stream) {
  const float* x = (const float*)d_in[0];
  const float* Wk = (const float*)d_in[1];
  const float* Wv = (const float*)d_in[2];
  const float* Wg = (const float*)d_in[3];
  const float* bg = (const float*)d_in[4];
  const float* Wo = (const float*)d_in[5];
  const float* bo = (const float*)d_in[6];

  float* out = (float*)d_out;                        // [8192][1024]
  float* err_out = out + (size_t)M_ROWS * 1024;      // [8192]

  char* ws = (char*)d_ws;
  float* KV = (float*)ws;                                        // 8192*512 f32
  float* gate = (float*)(ws + (size_t)M_ROWS * 512 * 4);         // 8192 f32
  unsigned short* ysbf =
      (unsigned short*)(ws + (size_t)M_ROWS * 512 * 4 + (size_t)M_ROWS * 4);

  gemm_kv<<<dim3(4, 64), 256, 0, stream>>>(x, Wk, Wv, KV);
  gate_kernel<<<dim3(2048), 256, 0, stream>>>(x, Wg, bg, gate);
  scan_kernel<<<dim3(8), 256, 0, stream>>>(KV, gate, ysbf, err_out);
  gemm_out<<<dim3(8, 64), 256, 0, stream>>>(ysbf, Wo, bo, out);
}

// Round 2
// 1657.183 us; speedup vs baseline: 1.0466x; 1.0466x over previous
//
#include <hip/hip_runtime.h>
#include <hip/hip_bf16.h>

#define B_DIM 8
#define S_DIM 1024
#define D_DIM 1024
#define N_DIM 256
#define M_ROWS (B_DIM * S_DIM) /* 8192 */

typedef __attribute__((ext_vector_type(8))) short bf16x8;
typedef __attribute__((ext_vector_type(8))) unsigned short u16x8;
typedef __attribute__((ext_vector_type(4))) float f32x4;

static __device__ __forceinline__ unsigned short f2bf(float f) {
  union { __hip_bfloat16 h; unsigned short s; } u;
  u.h = __float2bfloat16(f);
  return u.s;
}

// ---------------------------------------------------------------------------
// GEMM1: KV[8192][512] = x[8192][1024] @ [Wk;Wv]([512][1024])^T   (bf16 MFMA)
// ---------------------------------------------------------------------------
__global__ __launch_bounds__(256) void gemm_kv(const float* __restrict__ x,
                                               const float* __restrict__ Wk,
                                               const float* __restrict__ Wv,
                                               float* __restrict__ KV) {
  __shared__ unsigned short lsA[128 * 40];
  __shared__ unsigned short lsB[128 * 40];
  const int tid = threadIdx.x;
  const int row0 = blockIdx.y * 128;
  const int col0 = blockIdx.x * 128;
  const float* Bsrc = (col0 < 256) ? (Wk + (size_t)col0 * 1024)
                                   : (Wv + (size_t)(col0 - 256) * 1024);
  const int sr = tid >> 1, sh = tid & 1;
  const float* ap = x + (size_t)(row0 + sr) * 1024 + sh * 16;
  const float* bp = Bsrc + (size_t)sr * 1024 + sh * 16;
  unsigned short* wa = &lsA[sr * 40 + sh * 16];
  unsigned short* wb = &lsB[sr * 40 + sh * 16];

  const int lane = tid & 63;
  const int w = tid >> 6, wr = w >> 1, wc = w & 1;
  const int fr = lane & 15, fk = lane >> 4;

  f32x4 acc[4][4];
#pragma unroll
  for (int m = 0; m < 4; ++m)
#pragma unroll
    for (int n = 0; n < 4; ++n) acc[m][n] = (f32x4){0.f, 0.f, 0.f, 0.f};

  for (int kt = 0; kt < 32; ++kt) {
    const float* a = ap + kt * 32;
    const float* b = bp + kt * 32;
    f32x4 A0 = *(const f32x4*)(a + 0), A1 = *(const f32x4*)(a + 4);
    f32x4 A2 = *(const f32x4*)(a + 8), A3 = *(const f32x4*)(a + 12);
    f32x4 B0 = *(const f32x4*)(b + 0), B1 = *(const f32x4*)(b + 4);
    f32x4 B2 = *(const f32x4*)(b + 8), B3 = *(const f32x4*)(b + 12);
    u16x8 pa0, pa1, pb0, pb1;
#pragma unroll
    for (int e = 0; e < 4; ++e) {
      pa0[e] = f2bf(A0[e]); pa0[e + 4] = f2bf(A1[e]);
      pa1[e] = f2bf(A2[e]); pa1[e + 4] = f2bf(A3[e]);
      pb0[e] = f2bf(B0[e]); pb0[e + 4] = f2bf(B1[e]);
      pb1[e] = f2bf(B2[e]); pb1[e + 4] = f2bf(B3[e]);
    }
    *(u16x8*)wa = pa0; *(u16x8*)(wa + 8) = pa1;
    *(u16x8*)wb = pb0; *(u16x8*)(wb + 8) = pb1;
    __syncthreads();
    bf16x8 af[4], bfr[4];
#pragma unroll
    for (int m = 0; m < 4; ++m)
      af[m] = *(const bf16x8*)(&lsA[(wr * 64 + m * 16 + fr) * 40 + fk * 8]);
#pragma unroll
    for (int n = 0; n < 4; ++n)
      bfr[n] = *(const bf16x8*)(&lsB[(wc * 64 + n * 16 + fr) * 40 + fk * 8]);
#pragma unroll
    for (int m = 0; m < 4; ++m)
#pragma unroll
      for (int n = 0; n < 4; ++n)
        acc[m][n] = __builtin_amdgcn_mfma_f32_16x16x32_bf16(af[m], bfr[n],
                                                            acc[m][n], 0, 0, 0);
    __syncthreads();
  }
#pragma unroll
  for (int m = 0; m < 4; ++m)
#pragma unroll
    for (int n = 0; n < 4; ++n) {
      const int col = col0 + wc * 64 + n * 16 + fr;
#pragma unroll
      for (int r = 0; r < 4; ++r) {
        const int row = row0 + wr * 64 + m * 16 + fk * 4 + r;
        KV[(size_t)row * 512 + col] = acc[m][n][r];
      }
    }
}

// ---------------------------------------------------------------------------
// gate[8192] = sigmoid(x @ Wg^T + bg)
// ---------------------------------------------------------------------------
__global__ __launch_bounds__(256) void gate_kernel(const float* __restrict__ x,
                                                   const float* __restrict__ Wg,
                                                   const float* __restrict__ bg,
                                                   float* __restrict__ gate) {
  const int row = blockIdx.x * 4 + (threadIdx.x >> 6);
  const int lane = threadIdx.x & 63;
  const f32x4* xr = (const f32x4*)(x + (size_t)row * 1024);
  const f32x4* wg = (const f32x4*)Wg;
  float s = 0.f;
#pragma unroll
  for (int c = 0; c < 4; ++c) {
    f32x4 a = xr[lane + 64 * c];
    f32x4 wv = wg[lane + 64 * c];
    s += a[0] * wv[0] + a[1] * wv[1] + a[2] * wv[2] + a[3] * wv[3];
  }
#pragma unroll
  for (int off = 32; off >= 1; off >>= 1) s += __shfl_xor(s, off, 64);
  if (lane == 0) gate[row] = 1.f / (1.f + __expf(-(s + bg[0])));
}

// ---------------------------------------------------------------------------
// Sequential scan: 1 block per batch, 256 threads, thread (i,k).
// State in registers: w1[i][:,k], w2[i][:,k], w2T[i][:,k].
// ktj row loaded directly from global (2-step ping-pong prefetch);
// err row exchange via intra-wave LDS; err^2 reduced as local row sums.
// ---------------------------------------------------------------------------
__global__ __launch_bounds__(256) void scan_kernel(const float* __restrict__ KV,
                                                   const float* __restrict__ gate,
                                                   unsigned short* __restrict__ ysbf,
                                                   float* __restrict__ err_out) {
  const int b = blockIdx.x;
  const int tid = threadIdx.x;
  const int i = tid >> 4, k = tid & 15;

  __shared__ float hidT[2][16 * 20 + 4];  // stride 20: 2-way bank conflicts only
  __shared__ float errS[256];
  __shared__ __align__(16) float red[2][16];

  float w1c[16], w2c[16], w2t[16], eyek[16];
#pragma unroll
  for (int j = 0; j < 16; ++j) {
    const float v = (j == k) ? 1.f : 0.f;
    w1c[j] = v; w2c[j] = v; w2t[j] = v; eyek[j] = v;
  }
  float strength = 0.f, last_seen = 0.f, pend = 0.f;

  const float* Kb = KV + (size_t)b * S_DIM * 512;
  const float* Gb = gate + (size_t)b * S_DIM;
  unsigned short* Yb = ysbf + (size_t)b * S_DIM * 256;
  float* Eb = err_out + (size_t)b * S_DIM;

  // ping-pong prefetch buffers (depth 2)
  f32x4 kqA[4], kqB[4];
  float vtA, vtB, gA, gB;
  {
    const f32x4* p0 = (const f32x4*)(Kb + i * 16);
    kqA[0] = p0[0]; kqA[1] = p0[1]; kqA[2] = p0[2]; kqA[3] = p0[3];
    vtA = Kb[256 + tid]; gA = Gb[0];
    const f32x4* p1 = (const f32x4*)(Kb + 512 + i * 16);
    kqB[0] = p1[0]; kqB[1] = p1[1]; kqB[2] = p1[2]; kqB[3] = p1[3];
    vtB = Kb[512 + 256 + tid]; gB = Gb[1];
  }

  auto step = [&](int s, f32x4 (&kq)[4], float& vt, float& gv) {
    const int pb = s & 1;
    const float t = (float)(s + 1);

    // hidden[i][k] = sum_j kt[i][j] * w1[i][j][k]
    float a0 = 0.f, a1 = 0.f, a2 = 0.f, a3 = 0.f;
#pragma unroll
    for (int j = 0; j < 16; j += 4) {
      a0 = fmaf(kq[j >> 2][0], w1c[j], a0);
      a1 = fmaf(kq[j >> 2][1], w1c[j + 1], a1);
      a2 = fmaf(kq[j >> 2][2], w1c[j + 2], a2);
      a3 = fmaf(kq[j >> 2][3], w1c[j + 3], a3);
    }
    const float hidden = (a0 + a1) + (a2 + a3);
    hidT[pb][k * 20 + i] = hidden;
    __syncthreads();

    // hj[j] = hidden[j][i]  (row i, contiguous, 16B-aligned since 20*4*i % 16 == 0)
    float hj[16];
    {
      const f32x4* hp = (const f32x4*)&hidT[pb][i * 20];
      const f32x4 q0 = hp[0], q1 = hp[1], q2 = hp[2], q3 = hp[3];
#pragma unroll
      for (int e = 0; e < 4; ++e) {
        hj[e] = q0[e]; hj[4 + e] = q1[e]; hj[8 + e] = q2[e]; hj[12 + e] = q3[e];
      }
    }
    const float hkk = hidT[pb][i * 20 + k];  // hidden[k][i]

    // strength update with step s-1's err_norm (per-row partials in red)
    if (s > 0) {
      const f32x4* rp = (const f32x4*)&red[1 - pb][0];
      const f32x4 r0 = rp[0], r1 = rp[1], r2 = rp[2], r3 = rp[3];
      const f32x4 rs = (r0 + r1) + (r2 + r3);
      const float en = sqrtf((rs[0] + rs[1]) + (rs[2] + rs[3]));
      strength += pend / (1.f + en);
      if (tid == 0) Eb[s - 1] = en;
    }
    const float delta = t - last_seen;
    const float tg = 1.f / fmaxf(log1pf(delta * 0.1f), 1.f);
    const float df = 0.05f / (1.f + strength * tg);
    const float am = 1.f - df;

    // vt_pred[i][k] = sum_j hidden[j][i] * w2[i][j][k]
    float v0 = 0.f, v1 = 0.f, v2 = 0.f, v3 = 0.f;
#pragma unroll
    for (int j = 0; j < 16; j += 4) {
      v0 = fmaf(hj[j], w2c[j], v0);
      v1 = fmaf(hj[j + 1], w2c[j + 1], v1);
      v2 = fmaf(hj[j + 2], w2c[j + 2], v2);
      v3 = fmaf(hj[j + 3], w2c[j + 3], v3);
    }
    const float vt_pred = (v0 + v1) + (v2 + v3);
    Yb[(size_t)s * 256 + k * 16 + i] = f2bf(vt_pred);

    const float err = vt_pred - vt;

    // exchange err within the wave (rows of 16 lie inside one wave)
    errS[tid] = err;
    asm volatile("s_waitcnt lgkmcnt(0)" ::: "memory");
    float ej[16];
    {
      const f32x4* ep = (const f32x4*)&errS[i * 16];
      const f32x4 q0 = ep[0], q1 = ep[1], q2 = ep[2], q3 = ep[3];
#pragma unroll
      for (int e = 0; e < 4; ++e) {
        ej[e] = q0[e]; ej[4 + e] = q1[e]; ej[8 + e] = q2[e]; ej[12 + e] = q3[e];
      }
    }

    // per-row err^2 partial (local FMAs, no shuffle chain)
    float e0 = 0.f, e1 = 0.f, e2 = 0.f, e3 = 0.f;
#pragma unroll
    for (int j = 0; j < 16; j += 4) {
      e0 = fmaf(ej[j], ej[j], e0);
      e1 = fmaf(ej[j + 1], ej[j + 1], e1);
      e2 = fmaf(ej[j + 2], ej[j + 2], e2);
      e3 = fmaf(ej[j + 3], ej[j + 3], e3);
    }
    if (k == 0) red[pb][i] = (e0 + e1) + (e2 + e3);

    // grad_h[i][k] = sum_j err[i][j] * w2[i][k][j]
    float g0 = 0.f, g1 = 0.f, g2 = 0.f, g3 = 0.f;
#pragma unroll
    for (int j = 0; j < 16; j += 4) {
      g0 = fmaf(ej[j], w2t[j], g0);
      g1 = fmaf(ej[j + 1], w2t[j + 1], g1);
      g2 = fmaf(ej[j + 2], w2t[j + 2], g2);
      g3 = fmaf(ej[j + 3], w2t[j + 3], g3);
    }
    const float gh = (g0 + g1) + (g2 + g3);

    const float slr = 0.1f * gv;
    const float sg = slr * gh;
    const float se = slr * err;
    const float sh2 = slr * hkk;
#pragma unroll
    for (int j = 0; j < 16; ++j) {
      const float dfj = eyek[j] * df;
      w1c[j] = fmaf(fmaf(-sg, kq[j >> 2][j & 3], w1c[j]), am, dfj);
      w2c[j] = fmaf(fmaf(-se, hj[j], w2c[j]), am, dfj);
      w2t[j] = fmaf(fmaf(-sh2, ej[j], w2t[j]), am, dfj);
    }

    // activity / spacing / last_seen
    float s0 = 0.f, s1 = 0.f, s2 = 0.f, s3 = 0.f;
#pragma unroll
    for (int j = 0; j < 16; j += 4) {
      s0 = fmaf(kq[j >> 2][0], kq[j >> 2][0], s0);
      s1 = fmaf(kq[j >> 2][1], kq[j >> 2][1], s1);
      s2 = fmaf(kq[j >> 2][2], kq[j >> 2][2], s2);
      s3 = fmaf(kq[j >> 2][3], kq[j >> 2][3], s3);
    }
    const float act2 = (s0 + s1) + (s2 + s3);
    const float act = sqrtf(act2);
    pend = log1pf(delta) * act * gv * 0.05f;
    if (act2 > 0.01f) last_seen = t;

    // prefetch step s+2 into the same buffers (stray tail reads stay inside ws)
    {
      const float* base = Kb + (size_t)(s + 2) * 512;
      const f32x4* kp = (const f32x4*)(base + i * 16);
      kq[0] = kp[0]; kq[1] = kp[1]; kq[2] = kp[2]; kq[3] = kp[3];
      vt = base[256 + tid];
      gv = Gb[s + 2];
    }
  };

  for (int s = 0; s < S_DIM; s += 2) {
    step(s, kqA, vtA, gA);
    step(s + 1, kqB, vtB, gB);
  }
  __syncthreads();
  if (tid == 0) {
    const f32x4* rp = (const f32x4*)&red[1][0];  // s=1023 parity = 1
    const f32x4 r0 = rp[0], r1 = rp[1], r2 = rp[2], r3 = rp[3];
    const f32x4 rs = (r0 + r1) + (r2 + r3);
    Eb[S_DIM - 1] = sqrtf((rs[0] + rs[1]) + (rs[2] + rs[3]));
  }
}

// ---------------------------------------------------------------------------
// GEMM2: out[8192][1024] = ys[8192][256](bf16) @ Wo([1024][256])^T + bo
// ---------------------------------------------------------------------------
__global__ __launch_bounds__(256) void gemm_out(const unsigned short* __restrict__ ysbf,
                                                const float* __restrict__ Wo,
                                                const float* __restrict__ bo,
                                                float* __restrict__ out) {
  __shared__ unsigned short lsA[128 * 40];
  __shared__ unsigned short lsB[128 * 40];
  const int tid = threadIdx.x;
  const int row0 = blockIdx.y * 128;
  const int col0 = blockIdx.x * 128;
  const int sr = tid >> 1, sh = tid & 1;
  const unsigned short* ap = ysbf + (size_t)(row0 + sr) * 256 + sh * 16;
  const float* bp = Wo + (size_t)(col0 + sr) * 256 + sh * 16;
  unsigned short* wa = &lsA[sr * 40 + sh * 16];
  unsigned short* wb = &lsB[sr * 40 + sh * 16];

  const int lane = tid & 63;
  const int w = tid >> 6, wr = w >> 1, wc = w & 1;
  const int fr = lane & 15, fk = lane >> 4;

  f32x4 acc[4][4];
#pragma unroll
  for (int m = 0; m < 4; ++m)
#pragma unroll
    for (int n = 0; n < 4; ++n) acc[m][n] = (f32x4){0.f, 0.f, 0.f, 0.f};

  for (int kt = 0; kt < 8; ++kt) {
    u16x8 pa0 = *(const u16x8*)(ap + kt * 32);
    u16x8 pa1 = *(const u16x8*)(ap + kt * 32 + 8);
    const float* bq = bp + kt * 32;
    f32x4 B0 = *(const f32x4*)(bq + 0), B1 = *(const f32x4*)(bq + 4);
    f32x4 B2 = *(const f32x4*)(bq + 8), B3 = *(const f32x4*)(bq + 12);
    u16x8 pb0, pb1;
#pragma unroll
    for (int e = 0; e < 4; ++e) {
      pb0[e] = f2bf(B0[e]); pb0[e + 4] = f2bf(B1[e]);
      pb1[e] = f2bf(B2[e]); pb1[e + 4] = f2bf(B3[e]);
    }
    *(u16x8*)wa = pa0; *(u16x8*)(wa + 8) = pa1;
    *(u16x8*)wb = pb0; *(u16x8*)(wb + 8) = pb1;
    __syncthreads();
    bf16x8 af[4], bfr[4];
#pragma unroll
    for (int m = 0; m < 4; ++m)
      af[m] = *(const bf16x8*)(&lsA[(wr * 64 + m * 16 + fr) * 40 + fk * 8]);
#pragma unroll
    for (int n = 0; n < 4; ++n)
      bfr[n] = *(const bf16x8*)(&lsB[(wc * 64 + n * 16 + fr) * 40 + fk * 8]);
#pragma unroll
    for (int m = 0; m < 4; ++m)
#pragma unroll
      for (int n = 0; n < 4; ++n)
        acc[m][n] = __builtin_amdgcn_mfma_f32_16x16x32_bf16(af[m], bfr[n],
                                                            acc[m][n], 0, 0, 0);
    __syncthreads();
  }
#pragma unroll
  for (int m = 0; m < 4; ++m)
#pragma unroll
    for (int n = 0; n < 4; ++n) {
      const int col = col0 + wc * 64 + n * 16 + fr;
      const float bias = bo[col];
#pragma unroll
      for (int r = 0; r < 4; ++r) {
        const int row = row0 + wr * 64 + m * 16 + fk * 4 + r;
        out[(size_t)row * 1024 + col] = acc[m][n][r] + bias;
      }
    }
}

// ---------------------------------------------------------------------------
extern "C" void kernel_launch(void* const* d_in, const int* in_sizes, int n_in,
                              void* d_out, int out_size, void* d_ws, size_t ws_size,
                              hipStream_t stream) {
  const float* x = (const float*)d_in[0];
  const float* Wk = (const float*)d_in[1];
  const float* Wv = (const float*)d_in[2];
  const float* Wg = (const float*)d_in[3];
  const float* bg = (const float*)d_in[4];
  const float* Wo = (const float*)d_in[5];
  const float* bo = (const float*)d_in[6];

  float* out = (float*)d_out;                        // [8192][1024]
  float* err_out = out + (size_t)M_ROWS * 1024;      // [8192]

  char* ws = (char*)d_ws;
  float* KV = (float*)ws;                                        // 8192*512 f32
  float* gate = (float*)(ws + (size_t)M_ROWS * 512 * 4);         // 8192 f32
  unsigned short* ysbf =
      (unsigned short*)(ws + (size_t)M_ROWS * 512 * 4 + (size_t)M_ROWS * 4);

  gemm_kv<<<dim3(4, 64), 256, 0, stream>>>(x, Wk, Wv, KV);
  gate_kernel<<<dim3(2048), 256, 0, stream>>>(x, Wg, bg, gate);
  scan_kernel<<<dim3(8), 256, 0, stream>>>(KV, gate, ysbf, err_out);
  gemm_out<<<dim3(8, 64), 256, 0, stream>>>(ysbf, Wo, bo, out);
}

// Round 3
// 1593.366 us; speedup vs baseline: 1.0885x; 1.0401x over previous
//
#include <hip/hip_runtime.h>
#include <hip/hip_bf16.h>

#define B_DIM 8
#define S_DIM 1024
#define D_DIM 1024
#define N_DIM 256
#define M_ROWS (B_DIM * S_DIM) /* 8192 */

typedef __attribute__((ext_vector_type(8))) short bf16x8;
typedef __attribute__((ext_vector_type(8))) unsigned short u16x8;
typedef __attribute__((ext_vector_type(4))) float f32x4;

static __device__ __forceinline__ unsigned short f2bf(float f) {
  union { __hip_bfloat16 h; unsigned short s; } u;
  u.h = __float2bfloat16(f);
  return u.s;
}

// Barrier that does NOT drain vmcnt: LDS visibility only (lgkmcnt), so
// in-flight global prefetch loads survive across it. (__syncthreads would
// emit s_waitcnt vmcnt(0) and serialize the prefetch latency every step.)
#define LDS_BARRIER()                                         \
  do {                                                        \
    asm volatile("s_waitcnt lgkmcnt(0)" ::: "memory");        \
    __builtin_amdgcn_s_barrier();                             \
    asm volatile("" ::: "memory");                            \
  } while (0)

// ---------------------------------------------------------------------------
// GEMM1: KV[8192][512] = x[8192][1024] @ [Wk;Wv]([512][1024])^T   (bf16 MFMA)
// ---------------------------------------------------------------------------
__global__ __launch_bounds__(256) void gemm_kv(const float* __restrict__ x,
                                               const float* __restrict__ Wk,
                                               const float* __restrict__ Wv,
                                               float* __restrict__ KV) {
  __shared__ unsigned short lsA[128 * 40];
  __shared__ unsigned short lsB[128 * 40];
  const int tid = threadIdx.x;
  const int row0 = blockIdx.y * 128;
  const int col0 = blockIdx.x * 128;
  const float* Bsrc = (col0 < 256) ? (Wk + (size_t)col0 * 1024)
                                   : (Wv + (size_t)(col0 - 256) * 1024);
  const int sr = tid >> 1, sh = tid & 1;
  const float* ap = x + (size_t)(row0 + sr) * 1024 + sh * 16;
  const float* bp = Bsrc + (size_t)sr * 1024 + sh * 16;
  unsigned short* wa = &lsA[sr * 40 + sh * 16];
  unsigned short* wb = &lsB[sr * 40 + sh * 16];

  const int lane = tid & 63;
  const int w = tid >> 6, wr = w >> 1, wc = w & 1;
  const int fr = lane & 15, fk = lane >> 4;

  f32x4 acc[4][4];
#pragma unroll
  for (int m = 0; m < 4; ++m)
#pragma unroll
    for (int n = 0; n < 4; ++n) acc[m][n] = (f32x4){0.f, 0.f, 0.f, 0.f};

  for (int kt = 0; kt < 32; ++kt) {
    const float* a = ap + kt * 32;
    const float* b = bp + kt * 32;
    f32x4 A0 = *(const f32x4*)(a + 0), A1 = *(const f32x4*)(a + 4);
    f32x4 A2 = *(const f32x4*)(a + 8), A3 = *(const f32x4*)(a + 12);
    f32x4 B0 = *(const f32x4*)(b + 0), B1 = *(const f32x4*)(b + 4);
    f32x4 B2 = *(const f32x4*)(b + 8), B3 = *(const f32x4*)(b + 12);
    u16x8 pa0, pa1, pb0, pb1;
#pragma unroll
    for (int e = 0; e < 4; ++e) {
      pa0[e] = f2bf(A0[e]); pa0[e + 4] = f2bf(A1[e]);
      pa1[e] = f2bf(A2[e]); pa1[e + 4] = f2bf(A3[e]);
      pb0[e] = f2bf(B0[e]); pb0[e + 4] = f2bf(B1[e]);
      pb1[e] = f2bf(B2[e]); pb1[e + 4] = f2bf(B3[e]);
    }
    *(u16x8*)wa = pa0; *(u16x8*)(wa + 8) = pa1;
    *(u16x8*)wb = pb0; *(u16x8*)(wb + 8) = pb1;
    __syncthreads();
    bf16x8 af[4], bfr[4];
#pragma unroll
    for (int m = 0; m < 4; ++m)
      af[m] = *(const bf16x8*)(&lsA[(wr * 64 + m * 16 + fr) * 40 + fk * 8]);
#pragma unroll
    for (int n = 0; n < 4; ++n)
      bfr[n] = *(const bf16x8*)(&lsB[(wc * 64 + n * 16 + fr) * 40 + fk * 8]);
#pragma unroll
    for (int m = 0; m < 4; ++m)
#pragma unroll
      for (int n = 0; n < 4; ++n)
        acc[m][n] = __builtin_amdgcn_mfma_f32_16x16x32_bf16(af[m], bfr[n],
                                                            acc[m][n], 0, 0, 0);
    __syncthreads();
  }
#pragma unroll
  for (int m = 0; m < 4; ++m)
#pragma unroll
    for (int n = 0; n < 4; ++n) {
      const int col = col0 + wc * 64 + n * 16 + fr;
#pragma unroll
      for (int r = 0; r < 4; ++r) {
        const int row = row0 + wr * 64 + m * 16 + fk * 4 + r;
        KV[(size_t)row * 512 + col] = acc[m][n][r];
      }
    }
}

// ---------------------------------------------------------------------------
// gate[8192] = sigmoid(x @ Wg^T + bg)
// ---------------------------------------------------------------------------
__global__ __launch_bounds__(256) void gate_kernel(const float* __restrict__ x,
                                                   const float* __restrict__ Wg,
                                                   const float* __restrict__ bg,
                                                   float* __restrict__ gate) {
  const int row = blockIdx.x * 4 + (threadIdx.x >> 6);
  const int lane = threadIdx.x & 63;
  const f32x4* xr = (const f32x4*)(x + (size_t)row * 1024);
  const f32x4* wg = (const f32x4*)Wg;
  float s = 0.f;
#pragma unroll
  for (int c = 0; c < 4; ++c) {
    f32x4 a = xr[lane + 64 * c];
    f32x4 wv = wg[lane + 64 * c];
    s += a[0] * wv[0] + a[1] * wv[1] + a[2] * wv[2] + a[3] * wv[3];
  }
#pragma unroll
  for (int off = 32; off >= 1; off >>= 1) s += __shfl_xor(s, off, 64);
  if (lane == 0) gate[row] = 1.f / (1.f + __expf(-(s + bg[0])));
}

// ---------------------------------------------------------------------------
// Sequential scan: 1 block per batch, 256 threads, thread (i,k).
// State in registers: w1[i][:,k], w2[i][:,k], w2T[i][:,k].
// Global prefetch (depth 2) stays in flight across the LDS_BARRIER — no
// vmcnt(0) drain per step.
// ---------------------------------------------------------------------------
__global__ __launch_bounds__(256) void scan_kernel(const float* __restrict__ KV,
                                                   const float* __restrict__ gate,
                                                   unsigned short* __restrict__ ysbf,
                                                   float* __restrict__ err_out) {
  const int b = blockIdx.x;
  const int tid = threadIdx.x;
  const int i = tid >> 4, k = tid & 15;

  __shared__ float hidT[2][16 * 20 + 4];  // stride 20: 2-way bank conflicts only
  __shared__ float errS[256];
  __shared__ __align__(16) float red[2][16];

  float w1c[16], w2c[16], w2t[16], eyek[16];
#pragma unroll
  for (int j = 0; j < 16; ++j) {
    const float v = (j == k) ? 1.f : 0.f;
    w1c[j] = v; w2c[j] = v; w2t[j] = v; eyek[j] = v;
  }
  float strength = 0.f, last_seen = 0.f, pend = 0.f;

  const float* Kb = KV + (size_t)b * S_DIM * 512;
  const float* Gb = gate + (size_t)b * S_DIM;
  unsigned short* Yb = ysbf + (size_t)b * S_DIM * 256;
  float* Eb = err_out + (size_t)b * S_DIM;

  // ping-pong prefetch buffers (depth 2)
  f32x4 kqA[4], kqB[4];
  float vtA, vtB, gA, gB;
  {
    const f32x4* p0 = (const f32x4*)(Kb + i * 16);
    kqA[0] = p0[0]; kqA[1] = p0[1]; kqA[2] = p0[2]; kqA[3] = p0[3];
    vtA = Kb[256 + tid]; gA = Gb[0];
    const f32x4* p1 = (const f32x4*)(Kb + 512 + i * 16);
    kqB[0] = p1[0]; kqB[1] = p1[1]; kqB[2] = p1[2]; kqB[3] = p1[3];
    vtB = Kb[512 + 256 + tid]; gB = Gb[1];
  }

  auto step = [&](int s, f32x4 (&kq)[4], float& vt, float& gv) {
    const int pb = s & 1;
    const float t = (float)(s + 1);

    // hidden[i][k] = sum_j kt[i][j] * w1[i][j][k]
    float a0 = 0.f, a1 = 0.f, a2 = 0.f, a3 = 0.f;
#pragma unroll
    for (int j = 0; j < 16; j += 4) {
      a0 = fmaf(kq[j >> 2][0], w1c[j], a0);
      a1 = fmaf(kq[j >> 2][1], w1c[j + 1], a1);
      a2 = fmaf(kq[j >> 2][2], w1c[j + 2], a2);
      a3 = fmaf(kq[j >> 2][3], w1c[j + 3], a3);
    }
    const float hidden = (a0 + a1) + (a2 + a3);
    hidT[pb][k * 20 + i] = hidden;
    LDS_BARRIER();

    // hj[j] = hidden[j][i]  (row i, contiguous, 16B-aligned since 20*4*i % 16 == 0)
    float hj[16];
    {
      const f32x4* hp = (const f32x4*)&hidT[pb][i * 20];
      const f32x4 q0 = hp[0], q1 = hp[1], q2 = hp[2], q3 = hp[3];
#pragma unroll
      for (int e = 0; e < 4; ++e) {
        hj[e] = q0[e]; hj[4 + e] = q1[e]; hj[8 + e] = q2[e]; hj[12 + e] = q3[e];
      }
    }
    const float hkk = hidT[pb][i * 20 + k];  // hidden[k][i]

    // strength update with step s-1's err_norm (per-row partials in red)
    if (s > 0) {
      const f32x4* rp = (const f32x4*)&red[1 - pb][0];
      const f32x4 r0 = rp[0], r1 = rp[1], r2 = rp[2], r3 = rp[3];
      const f32x4 rs = (r0 + r1) + (r2 + r3);
      const float en = sqrtf((rs[0] + rs[1]) + (rs[2] + rs[3]));
      strength += pend / (1.f + en);
      if (tid == 0) Eb[s - 1] = en;
    }
    const float delta = t - last_seen;
    const float tg = 1.f / fmaxf(log1pf(delta * 0.1f), 1.f);
    const float df = 0.05f / (1.f + strength * tg);
    const float am = 1.f - df;

    // vt_pred[i][k] = sum_j hidden[j][i] * w2[i][j][k]
    float v0 = 0.f, v1 = 0.f, v2 = 0.f, v3 = 0.f;
#pragma unroll
    for (int j = 0; j < 16; j += 4) {
      v0 = fmaf(hj[j], w2c[j], v0);
      v1 = fmaf(hj[j + 1], w2c[j + 1], v1);
      v2 = fmaf(hj[j + 2], w2c[j + 2], v2);
      v3 = fmaf(hj[j + 3], w2c[j + 3], v3);
    }
    const float vt_pred = (v0 + v1) + (v2 + v3);
    Yb[(size_t)s * 256 + k * 16 + i] = f2bf(vt_pred);

    const float err = vt_pred - vt;

    // exchange err within the wave (rows of 16 lie inside one wave)
    errS[tid] = err;
    asm volatile("s_waitcnt lgkmcnt(0)" ::: "memory");
    float ej[16];
    {
      const f32x4* ep = (const f32x4*)&errS[i * 16];
      const f32x4 q0 = ep[0], q1 = ep[1], q2 = ep[2], q3 = ep[3];
#pragma unroll
      for (int e = 0; e < 4; ++e) {
        ej[e] = q0[e]; ej[4 + e] = q1[e]; ej[8 + e] = q2[e]; ej[12 + e] = q3[e];
      }
    }

    // per-row err^2 partial (local FMAs, no shuffle chain)
    float e0 = 0.f, e1 = 0.f, e2 = 0.f, e3 = 0.f;
#pragma unroll
    for (int j = 0; j < 16; j += 4) {
      e0 = fmaf(ej[j], ej[j], e0);
      e1 = fmaf(ej[j + 1], ej[j + 1], e1);
      e2 = fmaf(ej[j + 2], ej[j + 2], e2);
      e3 = fmaf(ej[j + 3], ej[j + 3], e3);
    }
    if (k == 0) red[pb][i] = (e0 + e1) + (e2 + e3);

    // grad_h[i][k] = sum_j err[i][j] * w2[i][k][j]
    float g0 = 0.f, g1 = 0.f, g2 = 0.f, g3 = 0.f;
#pragma unroll
    for (int j = 0; j < 16; j += 4) {
      g0 = fmaf(ej[j], w2t[j], g0);
      g1 = fmaf(ej[j + 1], w2t[j + 1], g1);
      g2 = fmaf(ej[j + 2], w2t[j + 2], g2);
      g3 = fmaf(ej[j + 3], w2t[j + 3], g3);
    }
    const float gh = (g0 + g1) + (g2 + g3);

    const float slr = 0.1f * gv;
    const float sg = slr * gh;
    const float se = slr * err;
    const float sh2 = slr * hkk;
#pragma unroll
    for (int j = 0; j < 16; ++j) {
      const float dfj = eyek[j] * df;
      w1c[j] = fmaf(fmaf(-sg, kq[j >> 2][j & 3], w1c[j]), am, dfj);
      w2c[j] = fmaf(fmaf(-se, hj[j], w2c[j]), am, dfj);
      w2t[j] = fmaf(fmaf(-sh2, ej[j], w2t[j]), am, dfj);
    }

    // activity / spacing / last_seen
    float s0 = 0.f, s1 = 0.f, s2 = 0.f, s3 = 0.f;
#pragma unroll
    for (int j = 0; j < 16; j += 4) {
      s0 = fmaf(kq[j >> 2][0], kq[j >> 2][0], s0);
      s1 = fmaf(kq[j >> 2][1], kq[j >> 2][1], s1);
      s2 = fmaf(kq[j >> 2][2], kq[j >> 2][2], s2);
      s3 = fmaf(kq[j >> 2][3], kq[j >> 2][3], s3);
    }
    const float act2 = (s0 + s1) + (s2 + s3);
    const float act = sqrtf(act2);
    pend = log1pf(delta) * act * gv * 0.05f;
    if (act2 > 0.01f) last_seen = t;

    // prefetch step s+2 into the same buffers (stray tail reads stay inside ws)
    {
      const float* base = Kb + (size_t)(s + 2) * 512;
      const f32x4* kp = (const f32x4*)(base + i * 16);
      kq[0] = kp[0]; kq[1] = kp[1]; kq[2] = kp[2]; kq[3] = kp[3];
      vt = base[256 + tid];
      gv = Gb[s + 2];
    }
  };

  for (int s = 0; s < S_DIM; s += 2) {
    step(s, kqA, vtA, gA);
    step(s + 1, kqB, vtB, gB);
  }
  LDS_BARRIER();
  if (tid == 0) {
    const f32x4* rp = (const f32x4*)&red[1][0];  // s=1023 parity = 1
    const f32x4 r0 = rp[0], r1 = rp[1], r2 = rp[2], r3 = rp[3];
    const f32x4 rs = (r0 + r1) + (r2 + r3);
    Eb[S_DIM - 1] = sqrtf((rs[0] + rs[1]) + (rs[2] + rs[3]));
  }
}

// ---------------------------------------------------------------------------
// GEMM2: out[8192][1024] = ys[8192][256](bf16) @ Wo([1024][256])^T + bo
// ---------------------------------------------------------------------------
__global__ __launch_bounds__(256) void gemm_out(const unsigned short* __restrict__ ysbf,
                                                const float* __restrict__ Wo,
                                                const float* __restrict__ bo,
                                                float* __restrict__ out) {
  __shared__ unsigned short lsA[128 * 40];
  __shared__ unsigned short lsB[128 * 40];
  const int tid = threadIdx.x;
  const int row0 = blockIdx.y * 128;
  const int col0 = blockIdx.x * 128;
  const int sr = tid >> 1, sh = tid & 1;
  const unsigned short* ap = ysbf + (size_t)(row0 + sr) * 256 + sh * 16;
  const float* bp = Wo + (size_t)(col0 + sr) * 256 + sh * 16;
  unsigned short* wa = &lsA[sr * 40 + sh * 16];
  unsigned short* wb = &lsB[sr * 40 + sh * 16];

  const int lane = tid & 63;
  const int w = tid >> 6, wr = w >> 1, wc = w & 1;
  const int fr = lane & 15, fk = lane >> 4;

  f32x4 acc[4][4];
#pragma unroll
  for (int m = 0; m < 4; ++m)
#pragma unroll
    for (int n = 0; n < 4; ++n) acc[m][n] = (f32x4){0.f, 0.f, 0.f, 0.f};

  for (int kt = 0; kt < 8; ++kt) {
    u16x8 pa0 = *(const u16x8*)(ap + kt * 32);
    u16x8 pa1 = *(const u16x8*)(ap + kt * 32 + 8);
    const float* bq = bp + kt * 32;
    f32x4 B0 = *(const f32x4*)(bq + 0), B1 = *(const f32x4*)(bq + 4);
    f32x4 B2 = *(const f32x4*)(bq + 8), B3 = *(const f32x4*)(bq + 12);
    u16x8 pb0, pb1;
#pragma unroll
    for (int e = 0; e < 4; ++e) {
      pb0[e] = f2bf(B0[e]); pb0[e + 4] = f2bf(B1[e]);
      pb1[e] = f2bf(B2[e]); pb1[e + 4] = f2bf(B3[e]);
    }
    *(u16x8*)wa = pa0; *(u16x8*)(wa + 8) = pa1;
    *(u16x8*)wb = pb0; *(u16x8*)(wb + 8) = pb1;
    __syncthreads();
    bf16x8 af[4], bfr[4];
#pragma unroll
    for (int m = 0; m < 4; ++m)
      af[m] = *(const bf16x8*)(&lsA[(wr * 64 + m * 16 + fr) * 40 + fk * 8]);
#pragma unroll
    for (int n = 0; n < 4; ++n)
      bfr[n] = *(const bf16x8*)(&lsB[(wc * 64 + n * 16 + fr) * 40 + fk * 8]);
#pragma unroll
    for (int m = 0; m < 4; ++m)
#pragma unroll
      for (int n = 0; n < 4; ++n)
        acc[m][n] = __builtin_amdgcn_mfma_f32_16x16x32_bf16(af[m], bfr[n],
                                                            acc[m][n], 0, 0, 0);
    __syncthreads();
  }
#pragma unroll
  for (int m = 0; m < 4; ++m)
#pragma unroll
    for (int n = 0; n < 4; ++n) {
      const int col = col0 + wc * 64 + n * 16 + fr;
      const float bias = bo[col];
#pragma unroll
      for (int r = 0; r < 4; ++r) {
        const int row = row0 + wr * 64 + m * 16 + fk * 4 + r;
        out[(size_t)row * 1024 + col] = acc[m][n][r] + bias;
      }
    }
}

// ---------------------------------------------------------------------------
extern "C" void kernel_launch(void* const* d_in, const int* in_sizes, int n_in,
                              void* d_out, int out_size, void* d_ws, size_t ws_size,
                              hipStream_t stream) {
  const float* x = (const float*)d_in[0];
  const float* Wk = (const float*)d_in[1];
  const float* Wv = (const float*)d_in[2];
  const float* Wg = (const float*)d_in[3];
  const float* bg = (const float*)d_in[4];
  const float* Wo = (const float*)d_in[5];
  const float* bo = (const float*)d_in[6];

  float* out = (float*)d_out;                        // [8192][1024]
  float* err_out = out + (size_t)M_ROWS * 1024;      // [8192]

  char* ws = (char*)d_ws;
  float* KV = (float*)ws;                                        // 8192*512 f32
  float* gate = (float*)(ws + (size_t)M_ROWS * 512 * 4);         // 8192 f32
  unsigned short* ysbf =
      (unsigned short*)(ws + (size_t)M_ROWS * 512 * 4 + (size_t)M_ROWS * 4);

  gemm_kv<<<dim3(4, 64), 256, 0, stream>>>(x, Wk, Wv, KV);
  gate_kernel<<<dim3(2048), 256, 0, stream>>>(x, Wg, bg, gate);
  scan_kernel<<<dim3(8), 256, 0, stream>>>(KV, gate, ysbf, err_out);
  gemm_out<<<dim3(8, 64), 256, 0, stream>>>(ysbf, Wo, bo, out);
}

// Round 4
// 1101.277 us; speedup vs baseline: 1.5749x; 1.4468x over previous
//
#include <hip/hip_runtime.h>
#include <hip/hip_bf16.h>

#define B_DIM 8
#define S_DIM 1024
#define D_DIM 1024
#define N_DIM 256
#define M_ROWS (B_DIM * S_DIM) /* 8192 */

typedef __attribute__((ext_vector_type(8))) short bf16x8;
typedef __attribute__((ext_vector_type(8))) unsigned short u16x8;
typedef __attribute__((ext_vector_type(4))) float f32x4;

static __device__ __forceinline__ unsigned short f2bf(float f) {
  union { __hip_bfloat16 h; unsigned short s; } u;
  u.h = __float2bfloat16(f);
  return u.s;
}

// ln(1+x), fast
static __device__ __forceinline__ float log1p_fast(float x) {
  return __logf(1.0f + x);
}

// Barrier that does NOT drain vmcnt: LDS visibility only.
#define LDS_BARRIER()                                         \
  do {                                                        \
    asm volatile("s_waitcnt lgkmcnt(0)" ::: "memory");        \
    __builtin_amdgcn_s_barrier();                             \
    asm volatile("" ::: "memory");                            \
  } while (0)

// ---------------------------------------------------------------------------
// GEMM1: KV[8192][512] = x[8192][1024] @ [Wk;Wv]([512][1024])^T   (bf16 MFMA)
// ---------------------------------------------------------------------------
__global__ __launch_bounds__(256) void gemm_kv(const float* __restrict__ x,
                                               const float* __restrict__ Wk,
                                               const float* __restrict__ Wv,
                                               float* __restrict__ KV) {
  __shared__ unsigned short lsA[128 * 40];
  __shared__ unsigned short lsB[128 * 40];
  const int tid = threadIdx.x;
  const int row0 = blockIdx.y * 128;
  const int col0 = blockIdx.x * 128;
  const float* Bsrc = (col0 < 256) ? (Wk + (size_t)col0 * 1024)
                                   : (Wv + (size_t)(col0 - 256) * 1024);
  const int sr = tid >> 1, sh = tid & 1;
  const float* ap = x + (size_t)(row0 + sr) * 1024 + sh * 16;
  const float* bp = Bsrc + (size_t)sr * 1024 + sh * 16;
  unsigned short* wa = &lsA[sr * 40 + sh * 16];
  unsigned short* wb = &lsB[sr * 40 + sh * 16];

  const int lane = tid & 63;
  const int w = tid >> 6, wr = w >> 1, wc = w & 1;
  const int fr = lane & 15, fk = lane >> 4;

  f32x4 acc[4][4];
#pragma unroll
  for (int m = 0; m < 4; ++m)
#pragma unroll
    for (int n = 0; n < 4; ++n) acc[m][n] = (f32x4){0.f, 0.f, 0.f, 0.f};

  for (int kt = 0; kt < 32; ++kt) {
    const float* a = ap + kt * 32;
    const float* b = bp + kt * 32;
    f32x4 A0 = *(const f32x4*)(a + 0), A1 = *(const f32x4*)(a + 4);
    f32x4 A2 = *(const f32x4*)(a + 8), A3 = *(const f32x4*)(a + 12);
    f32x4 B0 = *(const f32x4*)(b + 0), B1 = *(const f32x4*)(b + 4);
    f32x4 B2 = *(const f32x4*)(b + 8), B3 = *(const f32x4*)(b + 12);
    u16x8 pa0, pa1, pb0, pb1;
#pragma unroll
    for (int e = 0; e < 4; ++e) {
      pa0[e] = f2bf(A0[e]); pa0[e + 4] = f2bf(A1[e]);
      pa1[e] = f2bf(A2[e]); pa1[e + 4] = f2bf(A3[e]);
      pb0[e] = f2bf(B0[e]); pb0[e + 4] = f2bf(B1[e]);
      pb1[e] = f2bf(B2[e]); pb1[e + 4] = f2bf(B3[e]);
    }
    *(u16x8*)wa = pa0; *(u16x8*)(wa + 8) = pa1;
    *(u16x8*)wb = pb0; *(u16x8*)(wb + 8) = pb1;
    __syncthreads();
    bf16x8 af[4], bfr[4];
#pragma unroll
    for (int m = 0; m < 4; ++m)
      af[m] = *(const bf16x8*)(&lsA[(wr * 64 + m * 16 + fr) * 40 + fk * 8]);
#pragma unroll
    for (int n = 0; n < 4; ++n)
      bfr[n] = *(const bf16x8*)(&lsB[(wc * 64 + n * 16 + fr) * 40 + fk * 8]);
#pragma unroll
    for (int m = 0; m < 4; ++m)
#pragma unroll
      for (int n = 0; n < 4; ++n)
        acc[m][n] = __builtin_amdgcn_mfma_f32_16x16x32_bf16(af[m], bfr[n],
                                                            acc[m][n], 0, 0, 0);
    __syncthreads();
  }
#pragma unroll
  for (int m = 0; m < 4; ++m)
#pragma unroll
    for (int n = 0; n < 4; ++n) {
      const int col = col0 + wc * 64 + n * 16 + fr;
#pragma unroll
      for (int r = 0; r < 4; ++r) {
        const int row = row0 + wr * 64 + m * 16 + fk * 4 + r;
        KV[(size_t)row * 512 + col] = acc[m][n][r];
      }
    }
}

// ---------------------------------------------------------------------------
// gate[8192] = sigmoid(x @ Wg^T + bg)
// ---------------------------------------------------------------------------
__global__ __launch_bounds__(256) void gate_kernel(const float* __restrict__ x,
                                                   const float* __restrict__ Wg,
                                                   const float* __restrict__ bg,
                                                   float* __restrict__ gate) {
  const int row = blockIdx.x * 4 + (threadIdx.x >> 6);
  const int lane = threadIdx.x & 63;
  const f32x4* xr = (const f32x4*)(x + (size_t)row * 1024);
  const f32x4* wg = (const f32x4*)Wg;
  float s = 0.f;
#pragma unroll
  for (int c = 0; c < 4; ++c) {
    f32x4 a = xr[lane + 64 * c];
    f32x4 wv = wg[lane + 64 * c];
    s += a[0] * wv[0] + a[1] * wv[1] + a[2] * wv[2] + a[3] * wv[3];
  }
#pragma unroll
  for (int off = 32; off >= 1; off >>= 1) s += __shfl_xor(s, off, 64);
  if (lane == 0) gate[row] = 1.f / (1.f + __expf(-(s + bg[0])));
}

// ---------------------------------------------------------------------------
// WoP[d][i*16+k] = Wo[d][k*16+i]  (involution permute of columns)
// ---------------------------------------------------------------------------
__global__ __launch_bounds__(256) void wo_perm(const float* __restrict__ Wo,
                                               float* __restrict__ WoP) {
  const int d = blockIdx.x;
  const int c = threadIdx.x;
  WoP[(size_t)d * 256 + c] = Wo[(size_t)d * 256 + ((c & 15) * 16 + (c >> 4))];
}

// ---------------------------------------------------------------------------
// Sequential scan: 1 block per batch, 512 threads, thread (i,k,h):
// h in {0,1} owns j-slice [h*8, h*8+8) of w1[i][:,k], w2[i][:,k], w2T[i][:,k].
// Cross-half sums via __shfl_xor(.,1) (DPP). 2 waves/SIMD hide latency.
// ---------------------------------------------------------------------------
__global__ __launch_bounds__(512) void scan_kernel(const float* __restrict__ KV,
                                                   const float* __restrict__ gate,
                                                   unsigned short* __restrict__ ysbf,
                                                   float* __restrict__ err_out) {
  const int b = blockIdx.x;
  const int tid = threadIdx.x;       // 0..511
  const int i = tid >> 5;            // 0..15
  const int k = (tid >> 1) & 15;     // 0..15
  const int h = tid & 1;             // 0..1
  const int j0 = h * 8;

  __shared__ __align__(16) float hidT[2][16 * 20 + 4];  // stride 20
  __shared__ __align__(16) float errS[256];
  __shared__ __align__(16) float red[2][16];

  float w1c[8], w2c[8], w2t[8], eyek[8];
#pragma unroll
  for (int j = 0; j < 8; ++j) {
    const float v = ((j0 + j) == k) ? 1.f : 0.f;
    w1c[j] = v; w2c[j] = v; w2t[j] = v; eyek[j] = v;
  }
  float strength = 0.f, last_seen = 0.f, pend = 0.f;

  const float* Kb = KV + (size_t)b * S_DIM * 512;
  const float* Gb = gate + (size_t)b * S_DIM;
  unsigned short* Yb = ysbf + (size_t)b * S_DIM * 256;
  float* Eb = err_out + (size_t)b * S_DIM;

  // ping-pong prefetch buffers (depth 2)
  f32x4 kqA[2], kqB[2];
  float vtA, vtB, gA, gB;
  {
    kqA[0] = *(const f32x4*)(Kb + i * 16 + j0);
    kqA[1] = *(const f32x4*)(Kb + i * 16 + j0 + 4);
    vtA = Kb[256 + i * 16 + k]; gA = Gb[0];
    kqB[0] = *(const f32x4*)(Kb + 512 + i * 16 + j0);
    kqB[1] = *(const f32x4*)(Kb + 512 + i * 16 + j0 + 4);
    vtB = Kb[512 + 256 + i * 16 + k]; gB = Gb[1];
  }

  auto step = [&](int s, f32x4 (&kq)[2], float& vt, float& gv) {
    const int pb = s & 1;
    const float t = (float)(s + 1);

    // hidden[i][k] = sum_j kt[i][j] * w1[i][j][k]  (half-sum + DPP combine)
    float a0 = 0.f, a1 = 0.f, a2 = 0.f, a3 = 0.f;
#pragma unroll
    for (int j = 0; j < 8; j += 4) {
      a0 = fmaf(kq[j >> 2][0], w1c[j], a0);
      a1 = fmaf(kq[j >> 2][1], w1c[j + 1], a1);
      a2 = fmaf(kq[j >> 2][2], w1c[j + 2], a2);
      a3 = fmaf(kq[j >> 2][3], w1c[j + 3], a3);
    }
    const float hp = (a0 + a1) + (a2 + a3);
    const float hidden = hp + __shfl_xor(hp, 1, 64);
    hidT[pb][k * 20 + i] = hidden;  // both halves write same value (benign)
    LDS_BARRIER();

    // hj[j] = hidden[j0+j][i]
    float hj[8];
    {
      const f32x4* hp4 = (const f32x4*)&hidT[pb][i * 20];
      const f32x4 q0 = hp4[h * 2], q1 = hp4[h * 2 + 1];
#pragma unroll
      for (int e = 0; e < 4; ++e) { hj[e] = q0[e]; hj[4 + e] = q1[e]; }
    }
    const float hkk = hidT[pb][i * 20 + k];  // hidden[k][i]

    // strength update with step s-1's err_norm
    if (s > 0) {
      const f32x4* rp = (const f32x4*)&red[1 - pb][0];
      const f32x4 r0 = rp[0], r1 = rp[1], r2 = rp[2], r3 = rp[3];
      const f32x4 rs = (r0 + r1) + (r2 + r3);
      const float en = sqrtf((rs[0] + rs[1]) + (rs[2] + rs[3]));
      strength += pend * __builtin_amdgcn_rcpf(1.f + en);
      if (tid == 0) Eb[s - 1] = en;
    }
    const float delta = t - last_seen;
    const float m = fmaxf(log1p_fast(delta * 0.1f), 1.f);
    const float df = 0.05f * m * __builtin_amdgcn_rcpf(m + strength);
    const float am = 1.f - df;

    // vt_pred[i][k] = sum_j hidden[j][i] * w2[i][j][k]
    float v0 = 0.f, v1 = 0.f, v2 = 0.f, v3 = 0.f;
#pragma unroll
    for (int j = 0; j < 8; j += 4) {
      v0 = fmaf(hj[j], w2c[j], v0);
      v1 = fmaf(hj[j + 1], w2c[j + 1], v1);
      v2 = fmaf(hj[j + 2], w2c[j + 2], v2);
      v3 = fmaf(hj[j + 3], w2c[j + 3], v3);
    }
    const float vp = (v0 + v1) + (v2 + v3);
    const float vt_pred = vp + __shfl_xor(vp, 1, 64);
    if (h == 0) Yb[(size_t)s * 256 + i * 16 + k] = f2bf(vt_pred);  // coalesced

    const float err = vt_pred - vt;

    // row-broadcast err within wave (row i entirely inside one wave)
    errS[i * 16 + k] = err;  // 2 lanes, same value
    asm volatile("s_waitcnt lgkmcnt(0)" ::: "memory");
    float ej[8];
    {
      const f32x4* ep = (const f32x4*)&errS[i * 16 + j0];
      const f32x4 q0 = ep[0], q1 = ep[1];
#pragma unroll
      for (int e = 0; e < 4; ++e) { ej[e] = q0[e]; ej[4 + e] = q1[e]; }
    }

    // per-row err^2 (half + combine)
    float e0 = 0.f, e1 = 0.f, e2s = 0.f, e3 = 0.f;
#pragma unroll
    for (int j = 0; j < 8; j += 4) {
      e0 = fmaf(ej[j], ej[j], e0);
      e1 = fmaf(ej[j + 1], ej[j + 1], e1);
      e2s = fmaf(ej[j + 2], ej[j + 2], e2s);
      e3 = fmaf(ej[j + 3], ej[j + 3], e3);
    }
    const float e2p = (e0 + e1) + (e2s + e3);
    const float e2 = e2p + __shfl_xor(e2p, 1, 64);
    if ((tid & 31) == 0) red[pb][i] = e2;

    // grad_h[i][k] = sum_j err[i][j] * w2[i][k][j]
    float g0 = 0.f, g1 = 0.f, g2 = 0.f, g3 = 0.f;
#pragma unroll
    for (int j = 0; j < 8; j += 4) {
      g0 = fmaf(ej[j], w2t[j], g0);
      g1 = fmaf(ej[j + 1], w2t[j + 1], g1);
      g2 = fmaf(ej[j + 2], w2t[j + 2], g2);
      g3 = fmaf(ej[j + 3], w2t[j + 3], g3);
    }
    const float ghp = (g0 + g1) + (g2 + g3);
    const float gh = ghp + __shfl_xor(ghp, 1, 64);

    const float slr = 0.1f * gv;
    const float sg = slr * gh;
    const float se = slr * err;
    const float sh2 = slr * hkk;
#pragma unroll
    for (int j = 0; j < 8; ++j) {
      const float dfj = eyek[j] * df;
      const float ktj = kq[j >> 2][j & 3];
      w1c[j] = fmaf(fmaf(-sg, ktj, w1c[j]), am, dfj);
      w2c[j] = fmaf(fmaf(-se, hj[j], w2c[j]), am, dfj);
      w2t[j] = fmaf(fmaf(-sh2, ej[j], w2t[j]), am, dfj);
    }

    // activity / spacing / last_seen
    float s0 = 0.f, s1 = 0.f, s2 = 0.f, s3 = 0.f;
#pragma unroll
    for (int j = 0; j < 8; j += 4) {
      s0 = fmaf(kq[j >> 2][0], kq[j >> 2][0], s0);
      s1 = fmaf(kq[j >> 2][1], kq[j >> 2][1], s1);
      s2 = fmaf(kq[j >> 2][2], kq[j >> 2][2], s2);
      s3 = fmaf(kq[j >> 2][3], kq[j >> 2][3], s3);
    }
    const float a2p = (s0 + s1) + (s2 + s3);
    const float act2 = a2p + __shfl_xor(a2p, 1, 64);
    const float act = sqrtf(act2);
    pend = log1p_fast(delta) * act * gv * 0.05f;
    if (act2 > 0.01f) last_seen = t;

    // prefetch step s+2 (stray tail reads stay inside ws)
    {
      const float* base = Kb + (size_t)(s + 2) * 512;
      kq[0] = *(const f32x4*)(base + i * 16 + j0);
      kq[1] = *(const f32x4*)(base + i * 16 + j0 + 4);
      vt = base[256 + i * 16 + k];
      gv = Gb[s + 2];
    }
  };

  for (int s = 0; s < S_DIM; s += 2) {
    step(s, kqA, vtA, gA);
    step(s + 1, kqB, vtB, gB);
  }
  LDS_BARRIER();
  if (tid == 0) {
    const f32x4* rp = (const f32x4*)&red[1][0];  // s=1023 parity = 1
    const f32x4 r0 = rp[0], r1 = rp[1], r2 = rp[2], r3 = rp[3];
    const f32x4 rs = (r0 + r1) + (r2 + r3);
    Eb[S_DIM - 1] = sqrtf((rs[0] + rs[1]) + (rs[2] + rs[3]));
  }
}

// ---------------------------------------------------------------------------
// GEMM2: out[8192][1024] = ysP[8192][256](bf16) @ WoP([1024][256])^T + bo
// (ys and Wo columns both permuted by the i<->k involution; product unchanged)
// ---------------------------------------------------------------------------
__global__ __launch_bounds__(256) void gemm_out(const unsigned short* __restrict__ ysbf,
                                                const float* __restrict__ WoP,
                                                const float* __restrict__ bo,
                                                float* __restrict__ out) {
  __shared__ unsigned short lsA[128 * 40];
  __shared__ unsigned short lsB[128 * 40];
  const int tid = threadIdx.x;
  const int row0 = blockIdx.y * 128;
  const int col0 = blockIdx.x * 128;
  const int sr = tid >> 1, sh = tid & 1;
  const unsigned short* ap = ysbf + (size_t)(row0 + sr) * 256 + sh * 16;
  const float* bp = WoP + (size_t)(col0 + sr) * 256 + sh * 16;
  unsigned short* wa = &lsA[sr * 40 + sh * 16];
  unsigned short* wb = &lsB[sr * 40 + sh * 16];

  const int lane = tid & 63;
  const int w = tid >> 6, wr = w >> 1, wc = w & 1;
  const int fr = lane & 15, fk = lane >> 4;

  f32x4 acc[4][4];
#pragma unroll
  for (int m = 0; m < 4; ++m)
#pragma unroll
    for (int n = 0; n < 4; ++n) acc[m][n] = (f32x4){0.f, 0.f, 0.f, 0.f};

  for (int kt = 0; kt < 8; ++kt) {
    u16x8 pa0 = *(const u16x8*)(ap + kt * 32);
    u16x8 pa1 = *(const u16x8*)(ap + kt * 32 + 8);
    const float* bq = bp + kt * 32;
    f32x4 B0 = *(const f32x4*)(bq + 0), B1 = *(const f32x4*)(bq + 4);
    f32x4 B2 = *(const f32x4*)(bq + 8), B3 = *(const f32x4*)(bq + 12);
    u16x8 pb0, pb1;
#pragma unroll
    for (int e = 0; e < 4; ++e) {
      pb0[e] = f2bf(B0[e]); pb0[e + 4] = f2bf(B1[e]);
      pb1[e] = f2bf(B2[e]); pb1[e + 4] = f2bf(B3[e]);
    }
    *(u16x8*)wa = pa0; *(u16x8*)(wa + 8) = pa1;
    *(u16x8*)wb = pb0; *(u16x8*)(wb + 8) = pb1;
    __syncthreads();
    bf16x8 af[4], bfr[4];
#pragma unroll
    for (int m = 0; m < 4; ++m)
      af[m] = *(const bf16x8*)(&lsA[(wr * 64 + m * 16 + fr) * 40 + fk * 8]);
#pragma unroll
    for (int n = 0; n < 4; ++n)
      bfr[n] = *(const bf16x8*)(&lsB[(wc * 64 + n * 16 + fr) * 40 + fk * 8]);
#pragma unroll
    for (int m = 0; m < 4; ++m)
#pragma unroll
      for (int n = 0; n < 4; ++n)
        acc[m][n] = __builtin_amdgcn_mfma_f32_16x16x32_bf16(af[m], bfr[n],
                                                            acc[m][n], 0, 0, 0);
    __syncthreads();
  }
#pragma unroll
  for (int m = 0; m < 4; ++m)
#pragma unroll
    for (int n = 0; n < 4; ++n) {
      const int col = col0 + wc * 64 + n * 16 + fr;
      const float bias = bo[col];
#pragma unroll
      for (int r = 0; r < 4; ++r) {
        const int row = row0 + wr * 64 + m * 16 + fk * 4 + r;
        out[(size_t)row * 1024 + col] = acc[m][n][r] + bias;
      }
    }
}

// ---------------------------------------------------------------------------
extern "C" void kernel_launch(void* const* d_in, const int* in_sizes, int n_in,
                              void* d_out, int out_size, void* d_ws, size_t ws_size,
                              hipStream_t stream) {
  const float* x = (const float*)d_in[0];
  const float* Wk = (const float*)d_in[1];
  const float* Wv = (const float*)d_in[2];
  const float* Wg = (const float*)d_in[3];
  const float* bg = (const float*)d_in[4];
  const float* Wo = (const float*)d_in[5];
  const float* bo = (const float*)d_in[6];

  float* out = (float*)d_out;                        // [8192][1024]
  float* err_out = out + (size_t)M_ROWS * 1024;      // [8192]

  char* ws = (char*)d_ws;
  float* KV = (float*)ws;                                        // 16 MB
  float* gate = (float*)(ws + (size_t)M_ROWS * 512 * 4);         // 32 KB
  unsigned short* ysbf =
      (unsigned short*)(ws + (size_t)M_ROWS * 512 * 4 + 32768);  // 4 MB
  float* WoP = (float*)(ws + (size_t)M_ROWS * 512 * 4 + 32768 +
                        (size_t)M_ROWS * 256 * 2);               // 1 MB

  gemm_kv<<<dim3(4, 64), 256, 0, stream>>>(x, Wk, Wv, KV);
  gate_kernel<<<dim3(2048), 256, 0, stream>>>(x, Wg, bg, gate);
  wo_perm<<<dim3(1024), 256, 0, stream>>>(Wo, WoP);
  scan_kernel<<<dim3(8), 512, 0, stream>>>(KV, gate, ysbf, err_out);
  gemm_out<<<dim3(8, 64), 256, 0, stream>>>(ysbf, WoP, bo, out);
}